// Round 3
// baseline (563.038 us; speedup 1.0000x reference)
//
#include <hip/hip_runtime.h>
#include <hip/hip_bf16.h>

#define HWX 65536u    // 256*256
#define ROWS 10       // 8-row tile + 2 halo
#define RCELLS 34     // 32 cols + 2 halo; cell = 128 B (64 ci bf16), 16B chunks XOR-swizzled by ix&7

typedef __attribute__((ext_vector_type(8)))  __bf16 bf16x8;
typedef __attribute__((ext_vector_type(16))) float  f32x16;

__device__ __forceinline__ unsigned pk2(float lo, float hi) {
    __hip_bfloat162 p = __float22bfloat162_rn(make_float2(lo, hi));  // v_cvt_pk_bf16_f32
    union { __hip_bfloat162 b; unsigned u; } v; v.b = p; return v.u;
}

// Repack weights fp32 [co][ci][tap] -> bf16 A-frag table [(tap*4+kc)*2+h][co][j8] in d_ws.
__global__ void prep_weights(const float* __restrict__ wgt,
                             unsigned short* __restrict__ wsA) {
    int idx = blockIdx.x * 256 + threadIdx.x;
    if (idx >= 9 * 64 * 64) return;
    int j    = idx & 7;
    int co   = (idx >> 3) & 63;
    int rest = idx >> 9;                   // (tap*4+kc)*2 + h
    int h = rest & 1, kc = (rest >> 1) & 3, tap = rest >> 3;
    int ci = kc * 16 + h * 8 + j;
    __hip_bfloat16 b = __float2bfloat16(wgt[(co * 64 + ci) * 9 + tap]);
    union { __hip_bfloat16 b; unsigned short s; } v; v.b = b;
    wsA[idx] = v.s;
}

// Block: 512 thr = 8 waves; tile 64co x (8 rows x 32 cols); 2 x-adjacent tiles per block.
// LDS 43520 B -> 3 blocks/CU; acc = 2 x f32x16 (32 regs) + ~48 arch VGPR -> target 24 waves/CU.
// Wave: co-half = (wave&1)*32, row-pair = (wave>>1)*2.
__global__ __launch_bounds__(512, 6) void conv_mfma(
    const float* __restrict__ x, const unsigned short* __restrict__ wsA_in,
    const float* __restrict__ bias, float* __restrict__ out)
{
    __shared__ __align__(16) char s_in[ROWS * RCELLS * 128];   // 43520 B

    const int t    = threadIdx.x;
    const int l    = t & 63;
    const int wave = t >> 6;
    const int n    = l & 31;
    const int h    = l >> 5;
    const int co0  = (wave & 1) * 32;
    const int wrow = (wave >> 1) * 2;     // 2 output rows per wave

    const int bid   = (int)blockIdx.x;     // 2048 blocks
    const int xq    = bid & 3;
    const int strip = (bid >> 2) & 31;
    const int b     = bid >> 7;
    const int y0    = strip * 8;

    const int cp  = t >> 4;    // ci pair 0..31
    const int ixp = t & 15;    // column pair

    const float* xp0 = x + (size_t)(b * 64 + cp * 2) * HWX;

    for (int i = 0; i < 2; ++i) {
        const int x0 = (xq * 2 + i) * 32;

        // ---- stage interior: aligned full-line float2 runs, pack 2 ci -> 1 dword ----
        #pragma unroll 5
        for (int iy = 0; iy < ROWS; ++iy) {
            const int gy = y0 + iy - 1;
            float2 a = make_float2(0.f, 0.f), c = make_float2(0.f, 0.f);
            if ((unsigned)gy < 256u) {
                const float* p = xp0 + (unsigned)gy * 256u + (unsigned)(x0 + ixp * 2);
                a = *(const float2*)p;
                c = *(const float2*)(p + HWX);
            }
            const int ix0 = ixp * 2 + 1;                      // interior cells 1..32
            unsigned base = (unsigned)((iy * RCELLS + ix0) * 128);
            unsigned o0 = base + ((((cp >> 2) ^ (ix0 & 7)) << 4) | ((cp & 3) << 2));
            unsigned o1 = base + 128 + ((((cp >> 2) ^ ((ix0 + 1) & 7)) << 4) | ((cp & 3) << 2));
            *(unsigned*)(s_in + o0) = pk2(a.x, c.x);
            *(unsigned*)(s_in + o1) = pk2(a.y, c.y);
        }
        // ---- stage halo columns: cells ix=0 (gx=x0-1) and ix=33 (gx=x0+32) ----
        #pragma unroll
        for (int it = 0; it < 2; ++it) {
            int id = t + it * 512;
            if (id < 640) {
                int col = (id >= 320) ? 1 : 0;
                int r   = id - col * 320;
                int iy  = r >> 5;
                int cq  = r & 31;
                int gx  = col ? x0 + 32 : x0 - 1;
                int gy  = y0 + iy - 1;
                float f0 = 0.f, f1 = 0.f;
                if (((unsigned)gy < 256u) && ((unsigned)gx < 256u)) {
                    const float* q = x + (size_t)(b * 64 + cq * 2) * HWX
                                   + (unsigned)gy * 256u + (unsigned)gx;
                    f0 = q[0]; f1 = q[HWX];
                }
                int ix = col ? 33 : 0;
                unsigned off = (unsigned)((iy * RCELLS + ix) * 128)
                             + ((((cq >> 2) ^ (ix & 7)) << 4) | ((cq & 3) << 2));
                *(unsigned*)(s_in + off) = pk2(f0, f1);
            }
        }
        __syncthreads();

        // ---- compute: 48 ds_read_b128 feed 72 MFMA (B-frag reused across dy) ----
        // dx kept as a REAL loop (unroll 1): body = 24 MFMA + 12 ds_read + 3 af-loads,
        // live regs stay lean for the 24-waves/CU target. asm "+s" inside pins af-frag
        // loads to their iteration (no LICM hoist of 36 frags).
        const unsigned short* wp0 = wsA_in;

        f32x16 acc[2];
        #pragma unroll
        for (int r = 0; r < 2; ++r) acc[r] = (f32x16)0.0f;

        #pragma unroll 1
        for (int dx = 0; dx < 3; ++dx) {
            const unsigned short* wp = wp0;
            asm volatile("" : "+s"(wp));    // defeat LICM across dx iterations
            #pragma unroll
            for (int kc = 0; kc < 4; ++kc) {
                bf16x8 af[3];
                #pragma unroll
                for (int dy = 0; dy < 3; ++dy) {
                    const int tap = dy * 3 + dx;
                    af[dy] = *(const bf16x8*)(wp +
                        ((((tap * 4 + kc) * 2 + h) * 64 + co0 + n) * 8));
                }
                #pragma unroll
                for (int iyo = 0; iyo < 4; ++iyo) {
                    const int iy = wrow + iyo;
                    const int ix = n + dx;
                    const bf16x8 bf = *(const bf16x8*)(s_in
                        + (iy * RCELLS + ix) * 128 + (((kc * 2 + h) ^ (ix & 7)) << 4));
                    #pragma unroll
                    for (int dy = 0; dy < 3; ++dy) {
                        const int r = iyo - dy;
                        if (r >= 0 && r < 2)
                            acc[r] = __builtin_amdgcn_mfma_f32_32x32x16_bf16(
                                af[dy], bf, acc[r], 0, 0, 0);
                    }
                }
            }
        }
        __syncthreads();

        // ---- epilogue: bias + coalesced full-line stores ----
        const unsigned obase = (unsigned)(b * 64) * HWX + (unsigned)(x0 + n);
        #pragma unroll
        for (int reg = 0; reg < 16; ++reg) {
            const int row = (reg & 3) + 8 * (reg >> 2) + 4 * h;
            const float bb = bias[co0 + row];
            const unsigned cb = obase + (unsigned)(co0 + row) * HWX;
            #pragma unroll
            for (int r = 0; r < 2; ++r) {
                const unsigned Y = (unsigned)(y0 + wrow + r);
                out[cb + Y * 256u] = acc[r][reg] + bb;
            }
        }
    }
}

extern "C" void kernel_launch(void* const* d_in, const int* in_sizes, int n_in,
                              void* d_out, int out_size, void* d_ws, size_t ws_size,
                              hipStream_t stream) {
    const float* x    = (const float*)d_in[0];
    const float* wgt  = (const float*)d_in[1];
    const float* bias = (const float*)d_in[2];
    float* out = (float*)d_out;
    unsigned short* wsA = (unsigned short*)d_ws;   // 73728 B

    prep_weights<<<dim3(144), dim3(256), 0, stream>>>(wgt, wsA);
    conv_mfma<<<dim3(2048), dim3(512), 0, stream>>>(x, wsA, bias, out);
}

// Round 6
// 525.425 us; speedup vs baseline: 1.0716x; 1.0716x over previous
//
#include <hip/hip_runtime.h>
#include <hip/hip_bf16.h>

#define HWX 65536u    // 256*256
#define ROWS 18       // 16-row tile + 2 halo
#define RCELLS 34     // 32 cols + 2 halo; cell = 128 B (64 ci bf16), 16B chunks XOR-swizzled by ix&7
#define BUFB (ROWS * RCELLS * 128)   // 78336 B per buffer

typedef __attribute__((ext_vector_type(8)))  __bf16 bf16x8;
typedef __attribute__((ext_vector_type(16))) float  f32x16;

__device__ __forceinline__ unsigned pk2(float lo, float hi) {
    __hip_bfloat162 p = __float22bfloat162_rn(make_float2(lo, hi));  // v_cvt_pk_bf16_f32
    union { __hip_bfloat162 b; unsigned u; } v; v.b = p; return v.u;
}

// Repack weights fp32 [co][ci][tap] -> bf16 A-frag table [(tap*4+kc)*2+h][co][j8] in d_ws.
__global__ void prep_weights(const float* __restrict__ wgt,
                             unsigned short* __restrict__ wsA) {
    int idx = blockIdx.x * 256 + threadIdx.x;
    if (idx >= 9 * 64 * 64) return;
    int j    = idx & 7;
    int co   = (idx >> 3) & 63;
    int rest = idx >> 9;                   // (tap*4+kc)*2 + h
    int h = rest & 1, kc = (rest >> 1) & 3, tap = rest >> 3;
    int ci = kc * 16 + h * 8 + j;
    __hip_bfloat16 b = __float2bfloat16(wgt[(co * 64 + ci) * 9 + tap]);
    union { __hip_bfloat16 b; unsigned short s; } v; v.b = b;
    wsA[idx] = v.s;
}

// Register-carried staging payload: one 16-row tile of x (2 ci planes per thread)
// + halo-column slots. All indices static after full unroll -> stays in VGPRs.
struct StageRegs {
    float2 a[ROWS], c[ROWS];
    float  f0[3], f1[3];
};

__device__ __forceinline__ void stage_issue(StageRegs& S, const float* __restrict__ x,
                                            int b, int cp, int ixp, int t, int y0, int x0) {
    const float* xp0 = x + (size_t)(b * 64 + cp * 2) * HWX + (unsigned)(x0 + ixp * 2);
    #pragma unroll
    for (int iy = 0; iy < ROWS; ++iy) {
        const int gy = y0 + iy - 1;
        S.a[iy] = make_float2(0.f, 0.f);
        S.c[iy] = make_float2(0.f, 0.f);
        if ((unsigned)gy < 256u) {
            const float* p = xp0 + (unsigned)gy * 256u;
            S.a[iy] = *(const float2*)p;
            S.c[iy] = *(const float2*)(p + HWX);
        }
    }
    #pragma unroll
    for (int it = 0; it < 3; ++it) {
        const int id = t + it * 512;
        S.f0[it] = 0.f; S.f1[it] = 0.f;
        if (id < 1152) {
            const int col = (id >= 576) ? 1 : 0;
            const int r   = id - col * 576;
            const int iy  = r >> 5, cq = r & 31;
            const int gx  = col ? x0 + 32 : x0 - 1;
            const int gy  = y0 + iy - 1;
            if (((unsigned)gy < 256u) && ((unsigned)gx < 256u)) {
                const float* q = x + (size_t)(b * 64 + cq * 2) * HWX
                               + (unsigned)gy * 256u + (unsigned)gx;
                S.f0[it] = q[0]; S.f1[it] = q[HWX];
            }
        }
    }
}

__device__ __forceinline__ void stage_consume(const StageRegs& S, char* wr,
                                              int cp, int ixp, int t) {
    #pragma unroll
    for (int iy = 0; iy < ROWS; ++iy) {
        const int ix0 = ixp * 2 + 1;                      // interior cells 1..32
        unsigned base = (unsigned)((iy * RCELLS + ix0) * 128);
        unsigned o0 = base + ((((cp >> 2) ^ (ix0 & 7)) << 4) | ((cp & 3) << 2));
        unsigned o1 = base + 128 + ((((cp >> 2) ^ ((ix0 + 1) & 7)) << 4) | ((cp & 3) << 2));
        *(unsigned*)(wr + o0) = pk2(S.a[iy].x, S.c[iy].x);
        *(unsigned*)(wr + o1) = pk2(S.a[iy].y, S.c[iy].y);
    }
    #pragma unroll
    for (int it = 0; it < 3; ++it) {
        const int id = t + it * 512;
        if (id < 1152) {
            const int col = (id >= 576) ? 1 : 0;
            const int r   = id - col * 576;
            const int iy  = r >> 5, cq = r & 31;
            const int ix  = col ? 33 : 0;
            unsigned off = (unsigned)((iy * RCELLS + ix) * 128)
                         + ((((cq >> 2) ^ (ix & 7)) << 4) | ((cq & 3) << 2));
            *(unsigned*)(wr + off) = pk2(S.f0[it], S.f1[it]);
        }
    }
}

// Block: 512 thr = 8 waves; tile 64co x (16 rows x 32 cols); 8 x-tiles = full row per block.
// Double-buffered LDS (2 x 78336 B) -> 1 block/CU by design; T14 pipeline: loads for
// tile i+1 issued to regs BEFORE compute(i), converted+written to the other buffer after.
__global__ __launch_bounds__(512, 2) void conv_mfma(
    const float* __restrict__ x, const unsigned short* __restrict__ wsA_in,
    const float* __restrict__ bias, float* __restrict__ out)
{
    __shared__ __align__(16) char s_in[2 * BUFB];   // 156672 B

    const int t    = threadIdx.x;
    const int l    = t & 63;
    const int wave = t >> 6;
    const int n    = l & 31;
    const int h    = l >> 5;
    const int co0  = (wave & 1) * 32;
    const int wrow = (wave >> 1) * 4;

    const int bid0 = (int)blockIdx.x;                 // 256 blocks
    const int bid  = (bid0 & 7) * 32 + (bid0 >> 3);   // XCD-chunked swizzle (bijective, 256%8==0)
    const int strip = bid & 15;
    const int b     = bid >> 4;
    const int y0    = strip * 16;

    const int cp  = t >> 4;    // ci pair 0..31
    const int ixp = t & 15;    // column pair

    StageRegs S;
    stage_issue(S, x, b, cp, ixp, t, y0, 0);
    stage_consume(S, s_in, cp, ixp, t);
    __syncthreads();

    #pragma unroll 1
    for (int i = 0; i < 8; ++i) {
        const int x0 = i * 32;
        const char* rd = s_in + (i & 1) * BUFB;
        char*       wr = s_in + ((i + 1) & 1) * BUFB;

        // ---- T14: issue next tile's global loads before compute; they fly under it ----
        if (i < 7) stage_issue(S, x, b, cp, ixp, t, y0, x0 + 32);

        // ---- compute: 72 ds_read_b128 feed 144 MFMA (proven R2 body, reads rd) ----
        const unsigned short* wp0 = wsA_in;

        f32x16 acc[4];
        #pragma unroll
        for (int r = 0; r < 4; ++r) acc[r] = (f32x16)0.0f;

        #pragma unroll 1
        for (int dx = 0; dx < 3; ++dx) {
            const unsigned short* wp = wp0;
            asm volatile("" : "+s"(wp));    // defeat LICM across dx iterations
            #pragma unroll
            for (int kc = 0; kc < 4; ++kc) {
                bf16x8 af[3];
                #pragma unroll
                for (int dy = 0; dy < 3; ++dy) {
                    const int tap = dy * 3 + dx;
                    af[dy] = *(const bf16x8*)(wp +
                        ((((tap * 4 + kc) * 2 + h) * 64 + co0 + n) * 8));
                }
                #pragma unroll
                for (int iyo = 0; iyo < 6; ++iyo) {
                    const int iy = wrow + iyo;
                    const int ix = n + dx;
                    const bf16x8 bf = *(const bf16x8*)(rd
                        + (iy * RCELLS + ix) * 128 + (((kc * 2 + h) ^ (ix & 7)) << 4));
                    #pragma unroll
                    for (int dy = 0; dy < 3; ++dy) {
                        const int r = iyo - dy;
                        if (r >= 0 && r < 4)
                            acc[r] = __builtin_amdgcn_mfma_f32_32x32x16_bf16(
                                af[dy], bf, acc[r], 0, 0, 0);
                    }
                }
            }
        }

        // ---- convert + write next tile into the other buffer, then one barrier ----
        if (i < 7) stage_consume(S, wr, cp, ixp, t);
        __syncthreads();

        // ---- epilogue after barrier: stores overlap next tile's stage/compute ----
        const unsigned obase = (unsigned)(b * 64) * HWX + (unsigned)(x0 + n);
        #pragma unroll
        for (int reg = 0; reg < 16; ++reg) {
            const int row = (reg & 3) + 8 * (reg >> 2) + 4 * h;
            const float bb = bias[co0 + row];
            const unsigned cb = obase + (unsigned)(co0 + row) * HWX;
            #pragma unroll
            for (int r = 0; r < 4; ++r) {
                const unsigned Y = (unsigned)(y0 + wrow + r);
                out[cb + Y * 256u] = acc[r][reg] + bb;
            }
        }
    }
}

extern "C" void kernel_launch(void* const* d_in, const int* in_sizes, int n_in,
                              void* d_out, int out_size, void* d_ws, size_t ws_size,
                              hipStream_t stream) {
    const float* x    = (const float*)d_in[0];
    const float* wgt  = (const float*)d_in[1];
    const float* bias = (const float*)d_in[2];
    float* out = (float*)d_out;
    unsigned short* wsA = (unsigned short*)d_ws;   // 73728 B

    prep_weights<<<dim3(144), dim3(256), 0, stream>>>(wgt, wsA);
    conv_mfma<<<dim3(256), dim3(512), 0, stream>>>(x, wsA, bias, out);
}